// Round 13
// baseline (185.212 us; speedup 1.0000x reference)
//
#include <hip/hip_runtime.h>
#include <hip/hip_fp8.h>
#include <math.h>

#define N_NODES 100000
#define DIM 64
#define NUM_LAYER 3
#define BATCH 4096
#define REG_WEIGHT 1e-4f
#define NBUCKET 1563                           // dst >> 6 buckets (64 nodes each)
#define BSHIFT 6
#define BMASK 63
#define STAGE_CAP 1280                         // mean 819 + 16 sigma
#define CURPAD 16                              // ints: 64B pad per bucket cursor
#define H_SCALE 256.0f                         // fp8 store scale (values pre-scaled by dinv)
#define H_INV_SCALE (1.0f / 256.0f)

typedef float floatx2 __attribute__((ext_vector_type(2)));

// Scratch as device globals. Self-cleaning invariants (for graph replay):
//  - g_bcur: RELATIVE cursors, all-zero before stage_buckets; pull mode-1 re-zeros.
//  - g_shead: 0-sentinel (idx+1); pull mode-2 clears after walking chains.
// Probe ledger: fixed floor ~84us (2x 256MiB harness poison fills in timed
// region); pulls ~25us each (service-rate bound: ILP null R7, CSR variants
// null/regressed R7/R9); finalize ~16us; stage ~21us@EPT8. R10: device-scope
// __threadfence in wide grids = cross-XCD writeback storm (+74us) -> keep
// grid-wide reductions as separate kernels. R12: 1563 buckets (64 nodes) to
// kill intra-wave LDS same-address atomic serialization (64 lanes into 1563
// bins ~ unique vs 391's 3-4x multiplicity); finalize -> 1563x256 with
// block-stride prefix (R9-validated pattern) instead of 512-wide scan.
__device__ unsigned char g_hf8[2][(size_t)N_NODES * DIM]; // fp8 ping-pong Hs (scaled)
__device__ float g_sums[(size_t)3 * BATCH * DIM];  // sampled-row accumulators (f32)
__device__ int   g_row_ptr[N_NODES + 1];           // CSR row offsets (by dst)
__device__ float g_dinv[N_NODES];                  // deg^-0.5 (400 KB, L2-resident)
__device__ int   g_bcur[NBUCKET * CURPAD];         // padded bucket staging cursors (relative)
__device__ unsigned int g_stage[NBUCKET * STAGE_CAP]; // packed (src<<6)|(dst&63), 4B/edge
__device__ int   g_csr[1280000];                   // final CSR: src only, 4B/edge
__device__ int   g_shead[N_NODES];                 // node -> first sample idx+1 (0 = none)
__device__ int   g_snext[3 * BATCH];               // sample chain links (idx+1, 0 = end)
__device__ float g_part_sp[BATCH];                 // per-wave softplus partials
__device__ float g_part_rg[BATCH];                 // per-wave reg partials

// HW packed fp8 (OCP e4m3 on gfx950) converts: 2 values per instruction.
__device__ inline void fma4_fp8(unsigned int d, float w,
                                float& a0, float& a1, float& a2, float& a3) {
    floatx2 lo = __builtin_amdgcn_cvt_pk_f32_fp8((int)d, false);  // bytes 0,1
    floatx2 hi = __builtin_amdgcn_cvt_pk_f32_fp8((int)d, true);   // bytes 2,3
    a0 = fmaf(w, lo.x, a0); a1 = fmaf(w, lo.y, a1);
    a2 = fmaf(w, hi.x, a2); a3 = fmaf(w, hi.y, a3);
}
__device__ inline unsigned int pack4_fp8(float a0, float a1, float a2, float a3) {
    int w = __builtin_amdgcn_cvt_pk_fp8_f32(a0, a1, 0, false);
    w     = __builtin_amdgcn_cvt_pk_fp8_f32(a2, a3, w, true);
    return (unsigned int)w;
}

// ---- stage pass: LDS histogram -> padded global reservations -> sequential-run
//      4B stores. Also builds the sample chain map (0-sentinel). EPT=8 -> 157
//      blocks (contention sweet spot, R10/R11). 1563 bins: a wave's 64 keys are
//      ~unique -> LDS same-address atomic serialization eliminated. ----
#define EDGES_PER_THREAD 8
__global__ void __launch_bounds__(1024) stage_buckets(const int* __restrict__ src,
                                                      const int* __restrict__ dst, int E,
                                                      const int* __restrict__ users,
                                                      const int* __restrict__ pos,
                                                      const int* __restrict__ neg) {
    __shared__ int h[NBUCKET];
    __shared__ int cur[NBUCKET];
    int tid = threadIdx.x;
    int gt = blockIdx.x * 1024 + tid;
    if (gt < 3 * BATCH) {                       // build sample chains (12288 items)
        int which = gt / BATCH, s = gt - which * BATCH;
        const int* idx = (which == 0) ? users : ((which == 1) ? pos : neg);
        g_snext[gt] = atomicExch(&g_shead[idx[s]], gt + 1);   // 0-sentinel links
    }
    int base = blockIdx.x * (1024 * EDGES_PER_THREAD);
    for (int i = tid; i < NBUCKET; i += 1024) h[i] = 0;
    __syncthreads();
    int myd[EDGES_PER_THREAD], mys[EDGES_PER_THREAD];
    #pragma unroll
    for (int k = 0; k < EDGES_PER_THREAD; ++k) {
        int e = base + k * 1024 + tid;
        if (e < E) {
            myd[k] = dst[e]; mys[k] = src[e];
            atomicAdd(&h[myd[k] >> BSHIFT], 1);
        } else myd[k] = -1;
    }
    __syncthreads();
    for (int i = tid; i < NBUCKET; i += 1024) {
        int c = h[i];
        // relative reservation + absolute bucket base
        cur[i] = c ? (atomicAdd(&g_bcur[i * CURPAD], c) + i * STAGE_CAP) : 0;
    }
    __syncthreads();
    #pragma unroll
    for (int k = 0; k < EDGES_PER_THREAD; ++k) {
        if (myd[k] >= 0) {
            int p = atomicAdd(&cur[myd[k] >> BSHIFT], 1);      // LDS cursor -> slot
            g_stage[p] = (unsigned int)((mys[k] << BSHIFT) | (myd[k] & BMASK));
        }
    }
}

// ---- fused per-bucket (1563 blocks x 256): block-stride prefix over bucket
//      counts -> base; 64-bin hist + scan -> row_ptr/dinv; scatter into the
//      bucket's CSR window (src only, 4B); THEN convert the bucket's 64 emb
//      rows to the pre-weighted fp8 table Hs0 = dinv*emb. ----
__global__ void __launch_bounds__(256) finalize_place(const float* __restrict__ emb) {
    __shared__ int red[256];
    __shared__ int lh[64], sc[64], cur[64];
    __shared__ float ldv[64];
    int b = blockIdx.x, t = threadIdx.x;
    // (1) prefix base: sum of counts of all buckets before b (g_bcur is L2-hot)
    int sum = 0;
    for (int i = t; i < b; i += 256) sum += g_bcur[i * CURPAD];
    red[t] = sum;
    __syncthreads();
    for (int off = 128; off > 0; off >>= 1) {
        if (t < off) red[t] += red[t + off];
        __syncthreads();
    }
    int bbase = red[0];
    int cnt   = g_bcur[b * CURPAD];
    if (b == NBUCKET - 1 && t == 0) g_row_ptr[N_NODES] = bbase + cnt;
    int sbeg = b * STAGE_CAP;
    if (t < 64) lh[t] = 0;
    __syncthreads();
    // (2) 64-bin degree histogram of staged edges
    for (int k = t; k < cnt; k += 256)
        atomicAdd(&lh[g_stage[sbeg + k] & BMASK], 1);
    __syncthreads();
    int v = 0;
    if (t < 64) { v = lh[t]; sc[t] = v; }
    __syncthreads();
    for (int off = 1; off < 64; off <<= 1) {
        int x = (t >= off && t < 64) ? sc[t - off] : 0;
        __syncthreads();
        if (t < 64) sc[t] += x;
        __syncthreads();
    }
    int nbase = b << BSHIFT;
    int rows = N_NODES - nbase; if (rows > 64) rows = 64;
    if (t < 64) {
        int start = bbase + sc[t] - v;
        cur[t] = start;
        float dv = (v > 0) ? rsqrtf((float)v) : 0.0f;
        ldv[t] = dv;
        if (t < rows) {
            g_row_ptr[nbase + t] = start;                     // exclusive
            g_dinv[nbase + t]    = dv;
        }
    }
    __syncthreads();
    // (3) scatter into CSR window (staged chunk is L2-hot)
    for (int k = t; k < cnt; k += 256) {
        unsigned int e = g_stage[sbeg + k];
        int pos = atomicAdd(&cur[e & BMASK], 1);
        g_csr[pos] = (int)(e >> BSHIFT);                      // src only
    }
    // (4) fused conversion: bucket's rows -> Hs0 = SCALE * dinv[row] * emb[row]
    {
        unsigned int* hw = (unsigned int*)g_hf8[0];
        for (int idx = t; idx < rows * 16; idx += 256) {
            int row = idx >> 4, li = idx & 15;
            const float4 ev = *(const float4*)(emb + (size_t)(nbase + row) * DIM + li * 4);
            float s = ldv[row] * H_SCALE;
            hw[(size_t)(nbase + row) * 16 + li] =
                pack4_fp8(ev.x * s, ev.y * s, ev.z * s, ev.w * s);
        }
    }
}

// ---- pull one layer, FOUR nodes per wave (one 16-lane group per node).
//      Pre-weighted table (Hs = dinv*h): src-only 4B edge stream, no per-edge
//      weight. mode 1: g_sums = value, resets g_bcur, keeps chains.
//      mode 2: g_sums += value, consumes chains (g_shead -> 0). ----
__global__ void pull_layer_fp8(const unsigned char* __restrict__ h,
                               unsigned char* __restrict__ hn, int mode) {
    int gid0 = blockIdx.x * blockDim.x + threadIdx.x;
    if (mode == 1 && gid0 < NBUCKET) g_bcur[gid0 * CURPAD] = 0;  // reset for next replay
    int wid  = gid0 >> 6;
    int lane = threadIdx.x & 63;
    int g  = lane >> 4;      // group 0..3 -> node
    int li = lane & 15;      // dword index in row
    int n = wid * 4 + g;
    if (n >= N_NODES) return;                    // N_NODES % 4 == 0: whole waves retire
    int beg = g_row_ptr[n], end = g_row_ptr[n + 1];
    float dinvN = g_dinv[n];
    float a0 = 0.f, a1 = 0.f, a2 = 0.f, a3 = 0.f;
    for (int k = beg; k < end; k += 4) {
        int k1 = min(k + 1, end - 1);
        int k2 = min(k + 2, end - 1);
        int k3 = min(k + 3, end - 1);
        int s0 = g_csr[k];
        int s1 = g_csr[k1];
        int s2 = g_csr[k2];
        int s3 = g_csr[k3];
        unsigned int d0 = *(const unsigned int*)(h + (size_t)s0 * DIM + li * 4);
        unsigned int d1 = *(const unsigned int*)(h + (size_t)s1 * DIM + li * 4);
        unsigned int d2 = *(const unsigned int*)(h + (size_t)s2 * DIM + li * 4);
        unsigned int d3 = *(const unsigned int*)(h + (size_t)s3 * DIM + li * 4);
        float w1 = (k + 1 < end) ? 1.0f : 0.0f;
        float w2 = (k + 2 < end) ? 1.0f : 0.0f;
        float w3 = (k + 3 < end) ? 1.0f : 0.0f;
        fma4_fp8(d0, 1.0f, a0, a1, a2, a3);
        fma4_fp8(d1, w1, a0, a1, a2, a3);
        fma4_fp8(d2, w2, a0, a1, a2, a3);
        fma4_fp8(d3, w3, a0, a1, a2, a3);
    }
    float dd = dinvN * dinvN;                    // store next pre-weighted: dinv^2 * a
    *(unsigned int*)(hn + (size_t)n * DIM + li * 4) =
        pack4_fp8(a0 * dd, a1 * dd, a2 * dd, a3 * dd);
    if (mode) {
        float gw = dinvN * H_INV_SCALE;          // unscaled h value = a * dinv / SCALE
        int sidx = g_shead[n];                   // group-uniform chain walk (idx+1)
        while (sidx > 0) {
            int sr = sidx - 1;
            float* sp = &g_sums[(size_t)sr * DIM + li * 4];
            if (mode == 1) {
                sp[0] = a0 * gw; sp[1] = a1 * gw;
                sp[2] = a2 * gw; sp[3] = a3 * gw;
            } else {
                sp[0] += a0 * gw; sp[1] += a1 * gw;
                sp[2] += a2 * gw; sp[3] += a3 * gw;
            }
            sidx = g_snext[sr];
        }
        if (mode == 2 && li == 0) g_shead[n] = 0; // consume chains on layer 2
    }
}

// ---- final layer for sampled rows ONLY (4 samples/wave, same group scheme). ----
__global__ void pull_sampled(const unsigned char* __restrict__ h,
                             const int* __restrict__ users, const int* __restrict__ pos,
                             const int* __restrict__ neg) {
    int gid0 = blockIdx.x * blockDim.x + threadIdx.x;
    int wid  = gid0 >> 6;
    int lane = threadIdx.x & 63;
    int g  = lane >> 4;
    int li = lane & 15;
    int s = wid * 4 + g;
    if (s >= 3 * BATCH) return;
    int which = s >> 12;                         // / BATCH (4096)
    int i     = s & (BATCH - 1);
    const int* idx = (which == 0) ? users : ((which == 1) ? pos : neg);
    int node = idx[i];
    int beg = g_row_ptr[node], end = g_row_ptr[node + 1];
    float dinvN = g_dinv[node];
    float a0 = 0.f, a1 = 0.f, a2 = 0.f, a3 = 0.f;
    for (int k = beg; k < end; k += 4) {
        int k1 = min(k + 1, end - 1);
        int k2 = min(k + 2, end - 1);
        int k3 = min(k + 3, end - 1);
        int s0 = g_csr[k];
        int s1 = g_csr[k1];
        int s2 = g_csr[k2];
        int s3 = g_csr[k3];
        unsigned int d0 = *(const unsigned int*)(h + (size_t)s0 * DIM + li * 4);
        unsigned int d1 = *(const unsigned int*)(h + (size_t)s1 * DIM + li * 4);
        unsigned int d2 = *(const unsigned int*)(h + (size_t)s2 * DIM + li * 4);
        unsigned int d3 = *(const unsigned int*)(h + (size_t)s3 * DIM + li * 4);
        float w1 = (k + 1 < end) ? 1.0f : 0.0f;
        float w2 = (k + 2 < end) ? 1.0f : 0.0f;
        float w3 = (k + 3 < end) ? 1.0f : 0.0f;
        fma4_fp8(d0, 1.0f, a0, a1, a2, a3);
        fma4_fp8(d1, w1, a0, a1, a2, a3);
        fma4_fp8(d2, w2, a0, a1, a2, a3);
        fma4_fp8(d3, w3, a0, a1, a2, a3);
    }
    float gw = dinvN * H_INV_SCALE;
    float* sp = &g_sums[(size_t)s * DIM + li * 4];
    sp[0] += a0 * gw;
    sp[1] += a1 * gw;
    sp[2] += a2 * gw;
    sp[3] += a3 * gw;
}

// ---- per-sample scores + reg; layer-0 (emb) folded in here via u0/p0/n0 ----
__global__ void score_reduce(const float* __restrict__ emb,
                             const int* __restrict__ users, const int* __restrict__ pos,
                             const int* __restrict__ neg) {
    int wid  = (blockIdx.x * blockDim.x + threadIdx.x) >> 6;
    int lane = threadIdx.x & 63;
    if (wid >= BATCH) return;
    float u0 = emb[(size_t)users[wid] * DIM + lane];
    float p0 = emb[(size_t)pos[wid]   * DIM + lane];
    float n0 = emb[(size_t)neg[wid]   * DIM + lane];
    float u = 0.25f * (g_sums[(size_t)wid * DIM + lane] + u0);
    float p = 0.25f * (g_sums[(size_t)(BATCH + wid) * DIM + lane] + p0);
    float n = 0.25f * (g_sums[(size_t)(2 * BATCH + wid) * DIM + lane] + n0);
    float ps = u * p;
    float ns = u * n;
    float rg = u0 * u0 + p0 * p0 + n0 * n0;
    #pragma unroll
    for (int off = 32; off > 0; off >>= 1) {
        ps += __shfl_down(ps, off);
        ns += __shfl_down(ns, off);
        rg += __shfl_down(rg, off);
    }
    if (lane == 0) {
        float x  = ns - ps;
        float sp = fmaxf(x, 0.0f) + log1pf(expf(-fabsf(x)));  // stable softplus
        g_part_sp[wid] = sp;
        g_part_rg[wid] = rg;
    }
}

// ---- single-block final reduction over the 4096 per-wave partials ----
__global__ void final_reduce(float* __restrict__ out) {
    __shared__ float s_sp[256], s_rg[256];
    int t = threadIdx.x;
    float sp = 0.0f, rg = 0.0f;
    for (int i = t; i < BATCH; i += 256) { sp += g_part_sp[i]; rg += g_part_rg[i]; }
    s_sp[t] = sp; s_rg[t] = rg;
    __syncthreads();
    for (int off = 128; off > 0; off >>= 1) {
        if (t < off) { s_sp[t] += s_sp[t + off]; s_rg[t] += s_rg[t + off]; }
        __syncthreads();
    }
    if (t == 0) {
        float loss_emb = s_sp[0] / (float)BATCH;
        float reg      = 0.5f * s_rg[0] / (float)BATCH * REG_WEIGHT;
        out[0] = loss_emb + reg;
        out[1] = loss_emb;
        out[2] = reg;
    }
}

extern "C" void kernel_launch(void* const* d_in, const int* in_sizes, int n_in,
                              void* d_out, int out_size, void* d_ws, size_t ws_size,
                              hipStream_t stream) {
    const float* emb   = (const float*)d_in[0];
    const int*   src   = (const int*)d_in[1];
    const int*   dst   = (const int*)d_in[2];
    const int*   users = (const int*)d_in[3];
    const int*   pos   = (const int*)d_in[4];
    const int*   neg   = (const int*)d_in[5];
    const int E = in_sizes[1];
    float* out = (float*)d_out;

    unsigned char* hf_a;  hipGetSymbolAddress((void**)&hf_a, HIP_SYMBOL(g_hf8));
    unsigned char* hf_b = hf_a + (size_t)N_NODES * DIM;

    const int STAGE_BLOCKS = (E + 1024 * EDGES_PER_THREAD - 1) / (1024 * EDGES_PER_THREAD);
    stage_buckets<<<STAGE_BLOCKS, 1024, 0, stream>>>(src, dst, E, users, pos, neg);
    finalize_place<<<NBUCKET, 256, 0, stream>>>(emb);

    const int NQUAD = (N_NODES + 3) / 4;           // 4 nodes per wave
    const int PULL_BLOCKS = (NQUAD * 64 + 255) / 256;

    // layer 1: full pull + sampled gather (assign) + bcur reset
    pull_layer_fp8<<<PULL_BLOCKS, 256, 0, stream>>>(hf_a, hf_b, 1);

    // layer 2: full pull + sampled gather (accumulate) + chain consume
    pull_layer_fp8<<<PULL_BLOCKS, 256, 0, stream>>>(hf_b, hf_a, 2);

    // layer 3 sampled pull (4 samples/wave)
    const int SAMP_BLOCKS = ((3 * BATCH + 3) / 4 * 64 + 255) / 256;
    pull_sampled<<<SAMP_BLOCKS, 256, 0, stream>>>(hf_a, users, pos, neg);

    score_reduce<<<(BATCH * 64 + 255) / 256, 256, 0, stream>>>(emb, users, pos, neg);
    final_reduce<<<1, 256, 0, stream>>>(out);
}

// Round 14
// 182.625 us; speedup vs baseline: 1.0142x; 1.0142x over previous
//
#include <hip/hip_runtime.h>
#include <hip/hip_fp8.h>
#include <math.h>

#define N_NODES 100000
#define DIM 64
#define NUM_LAYER 3
#define BATCH 4096
#define REG_WEIGHT 1e-4f
#define NBUCKET 391                            // dst >> 8 buckets (256 nodes each)
#define STAGE_CAP 4096                         // fixed staging capacity per bucket (14 sigma)
#define CURPAD 16                              // ints: 64B pad per bucket cursor
#define H_SCALE 256.0f                         // fp8 store scale (values pre-scaled by dinv)
#define H_INV_SCALE (1.0f / 256.0f)

typedef float floatx2 __attribute__((ext_vector_type(2)));

// Scratch as device globals. Self-cleaning invariants (for graph replay):
//  - g_bcur: RELATIVE cursors, all-zero before stage_buckets; pull mode-1 re-zeros.
//  - g_shead: 0-sentinel (idx+1); pull mode-2 clears after walking chains.
// FINAL LEDGER (probe-audited): fixed floor ~84us (2x 256MiB harness poison
// fills in timed region); pulls ~25us each (random-64B gather service-rate,
// ~3.3 TB/s effective; table 6.4MB > 4MB/XCD L2; ILP null R7, wCSR null R4,
// global-atomic build -8x R9); stage ~17-21us (EPT8 best R11; 1563-bucket
// null R13); finalize ~16us (restructure null R13); tails ~8us (ticket
// fusion +74us R10: device-scope fence in wide grid = cross-XCD storm).
// This is R11 verbatim -- the measured best (181.6us).
__device__ unsigned char g_hf8[2][(size_t)N_NODES * DIM]; // fp8 ping-pong Hs (scaled)
__device__ float g_sums[(size_t)3 * BATCH * DIM];  // sampled-row accumulators (f32)
__device__ int   g_row_ptr[N_NODES + 1];           // CSR row offsets (by dst)
__device__ float g_dinv[N_NODES];                  // deg^-0.5 (400 KB, L2-resident)
__device__ int   g_bcur[NBUCKET * CURPAD];         // padded bucket staging cursors (relative)
__device__ unsigned int g_stage[NBUCKET * STAGE_CAP]; // packed (src<<8)|(dst&255), 4B/edge
__device__ int   g_csr[1280000];                   // final CSR: src only, 4B/edge
__device__ int   g_shead[N_NODES];                 // node -> first sample idx+1 (0 = none)
__device__ int   g_snext[3 * BATCH];               // sample chain links (idx+1, 0 = end)
__device__ float g_part_sp[BATCH];                 // per-wave softplus partials
__device__ float g_part_rg[BATCH];                 // per-wave reg partials

// HW packed fp8 (OCP e4m3 on gfx950) converts: 2 values per instruction.
__device__ inline void fma4_fp8(unsigned int d, float w,
                                float& a0, float& a1, float& a2, float& a3) {
    floatx2 lo = __builtin_amdgcn_cvt_pk_f32_fp8((int)d, false);  // bytes 0,1
    floatx2 hi = __builtin_amdgcn_cvt_pk_f32_fp8((int)d, true);   // bytes 2,3
    a0 = fmaf(w, lo.x, a0); a1 = fmaf(w, lo.y, a1);
    a2 = fmaf(w, hi.x, a2); a3 = fmaf(w, hi.y, a3);
}
__device__ inline unsigned int pack4_fp8(float a0, float a1, float a2, float a3) {
    int w = __builtin_amdgcn_cvt_pk_fp8_f32(a0, a1, 0, false);
    w     = __builtin_amdgcn_cvt_pk_fp8_f32(a2, a3, w, true);
    return (unsigned int)w;
}

// ---- stage pass: LDS histogram -> padded global reservations -> sequential-run
//      4B stores. Also builds the sample chain map (0-sentinel). EPT=8 -> 157
//      blocks: halves the 391-cursor reservation contention vs EPT=4's 313. ----
#define EDGES_PER_THREAD 8
__global__ void __launch_bounds__(1024) stage_buckets(const int* __restrict__ src,
                                                      const int* __restrict__ dst, int E,
                                                      const int* __restrict__ users,
                                                      const int* __restrict__ pos,
                                                      const int* __restrict__ neg) {
    __shared__ int h[NBUCKET];
    __shared__ int cur[NBUCKET];
    int tid = threadIdx.x;
    int gt = blockIdx.x * 1024 + tid;
    if (gt < 3 * BATCH) {                       // build sample chains (12288 items)
        int which = gt / BATCH, s = gt - which * BATCH;
        const int* idx = (which == 0) ? users : ((which == 1) ? pos : neg);
        g_snext[gt] = atomicExch(&g_shead[idx[s]], gt + 1);   // 0-sentinel links
    }
    int base = blockIdx.x * (1024 * EDGES_PER_THREAD);
    for (int i = tid; i < NBUCKET; i += 1024) h[i] = 0;
    __syncthreads();
    int myd[EDGES_PER_THREAD], mys[EDGES_PER_THREAD];
    #pragma unroll
    for (int k = 0; k < EDGES_PER_THREAD; ++k) {
        int e = base + k * 1024 + tid;
        if (e < E) {
            myd[k] = dst[e]; mys[k] = src[e];
            atomicAdd(&h[myd[k] >> 8], 1);
        } else myd[k] = -1;
    }
    __syncthreads();
    for (int i = tid; i < NBUCKET; i += 1024) {
        int c = h[i];
        // relative reservation + absolute bucket base
        cur[i] = c ? (atomicAdd(&g_bcur[i * CURPAD], c) + i * STAGE_CAP) : 0;
    }
    __syncthreads();
    #pragma unroll
    for (int k = 0; k < EDGES_PER_THREAD; ++k) {
        if (myd[k] >= 0) {
            int p = atomicAdd(&cur[myd[k] >> 8], 1);          // LDS cursor -> slot
            g_stage[p] = (unsigned int)((mys[k] << 8) | (myd[k] & 255));
        }
    }
}

// ---- fused per-bucket: 391-scan for base + degree hist + scan -> row_ptr/dinv,
//      scatter into the bucket's CSR window (src only, 4B), THEN convert this
//      bucket's 256 emb rows to the pre-weighted fp8 table Hs0 = dinv*emb. ----
__global__ void __launch_bounds__(512) finalize_place(const float* __restrict__ emb) {
    __shared__ int cs[512];
    __shared__ int lh[256], sc[256], cur[256];
    __shared__ float ldv[256];
    int b = blockIdx.x, t = threadIdx.x;
    int c = (t < NBUCKET) ? g_bcur[t * CURPAD] : 0;           // relative counts
    cs[t] = c;
    __syncthreads();
    for (int off = 1; off < 512; off <<= 1) {
        int x = (t >= off) ? cs[t - off] : 0;
        __syncthreads();
        cs[t] += x;
        __syncthreads();
    }
    int mybase = (b > 0) ? cs[b - 1] : 0;         // exclusive prefix at bucket b
    int cnt    = cs[b] - mybase;
    if (b == 0 && t == 0) g_row_ptr[N_NODES] = cs[NBUCKET - 1];
    int sbeg = b * STAGE_CAP;
    if (t < 256) lh[t] = 0;
    __syncthreads();
    for (int k = t; k < cnt; k += 512)
        atomicAdd(&lh[g_stage[sbeg + k] & 255], 1);
    __syncthreads();
    int v = 0;
    if (t < 256) { v = lh[t]; sc[t] = v; }
    __syncthreads();
    for (int off = 1; off < 256; off <<= 1) {
        int x = (t >= off && t < 256) ? sc[t - off] : 0;
        __syncthreads();
        if (t < 256) sc[t] += x;
        __syncthreads();
    }
    if (t < 256) {
        int start = mybase + sc[t] - v;
        cur[t] = start;
        float dv = (v > 0) ? rsqrtf((float)v) : 0.0f;
        ldv[t] = dv;
        int node = (b << 8) + t;
        if (node < N_NODES) {
            g_row_ptr[node] = start;                          // exclusive
            g_dinv[node]    = dv;
        }
    }
    __syncthreads();
    for (int k = t; k < cnt; k += 512) {                      // staged chunk is L2-hot
        unsigned int e = g_stage[sbeg + k];
        int pos = atomicAdd(&cur[e & 255], 1);
        g_csr[pos] = (int)(e >> 8);                           // src only
    }
    // fused conversion: this bucket's rows -> Hs0 = SCALE * dinv[row] * emb[row]
    {
        int nbase = b << 8;
        int rows = N_NODES - nbase; if (rows > 256) rows = 256;
        unsigned int* hw = (unsigned int*)g_hf8[0];
        for (int idx = t; idx < rows * 16; idx += 512) {
            int row = idx >> 4, li = idx & 15;
            const float4 ev = *(const float4*)(emb + (size_t)(nbase + row) * DIM + li * 4);
            float s = ldv[row] * H_SCALE;
            hw[(size_t)(nbase + row) * 16 + li] =
                pack4_fp8(ev.x * s, ev.y * s, ev.z * s, ev.w * s);
        }
    }
}

// ---- pull one layer, FOUR nodes per wave (one 16-lane group per node).
//      Pre-weighted table (Hs = dinv*h): src-only 4B edge stream, no per-edge
//      weight. mode 1: g_sums = value, resets g_bcur, keeps chains.
//      mode 2: g_sums += value, consumes chains (g_shead -> 0). ----
__global__ void pull_layer_fp8(const unsigned char* __restrict__ h,
                               unsigned char* __restrict__ hn, int mode) {
    int gid0 = blockIdx.x * blockDim.x + threadIdx.x;
    if (mode == 1 && gid0 < NBUCKET) g_bcur[gid0 * CURPAD] = 0;  // reset for next replay
    int wid  = gid0 >> 6;
    int lane = threadIdx.x & 63;
    int g  = lane >> 4;      // group 0..3 -> node
    int li = lane & 15;      // dword index in row
    int n = wid * 4 + g;
    if (n >= N_NODES) return;                    // N_NODES % 4 == 0: whole waves retire
    int beg = g_row_ptr[n], end = g_row_ptr[n + 1];
    float dinvN = g_dinv[n];
    float a0 = 0.f, a1 = 0.f, a2 = 0.f, a3 = 0.f;
    for (int k = beg; k < end; k += 4) {
        int k1 = min(k + 1, end - 1);
        int k2 = min(k + 2, end - 1);
        int k3 = min(k + 3, end - 1);
        int s0 = g_csr[k];
        int s1 = g_csr[k1];
        int s2 = g_csr[k2];
        int s3 = g_csr[k3];
        unsigned int d0 = *(const unsigned int*)(h + (size_t)s0 * DIM + li * 4);
        unsigned int d1 = *(const unsigned int*)(h + (size_t)s1 * DIM + li * 4);
        unsigned int d2 = *(const unsigned int*)(h + (size_t)s2 * DIM + li * 4);
        unsigned int d3 = *(const unsigned int*)(h + (size_t)s3 * DIM + li * 4);
        float w1 = (k + 1 < end) ? 1.0f : 0.0f;
        float w2 = (k + 2 < end) ? 1.0f : 0.0f;
        float w3 = (k + 3 < end) ? 1.0f : 0.0f;
        fma4_fp8(d0, 1.0f, a0, a1, a2, a3);
        fma4_fp8(d1, w1, a0, a1, a2, a3);
        fma4_fp8(d2, w2, a0, a1, a2, a3);
        fma4_fp8(d3, w3, a0, a1, a2, a3);
    }
    float dd = dinvN * dinvN;                    // store next pre-weighted: dinv^2 * a
    *(unsigned int*)(hn + (size_t)n * DIM + li * 4) =
        pack4_fp8(a0 * dd, a1 * dd, a2 * dd, a3 * dd);
    if (mode) {
        float gw = dinvN * H_INV_SCALE;          // unscaled h value = a * dinv / SCALE
        int sidx = g_shead[n];                   // group-uniform chain walk (idx+1)
        while (sidx > 0) {
            int sr = sidx - 1;
            float* sp = &g_sums[(size_t)sr * DIM + li * 4];
            if (mode == 1) {
                sp[0] = a0 * gw; sp[1] = a1 * gw;
                sp[2] = a2 * gw; sp[3] = a3 * gw;
            } else {
                sp[0] += a0 * gw; sp[1] += a1 * gw;
                sp[2] += a2 * gw; sp[3] += a3 * gw;
            }
            sidx = g_snext[sr];
        }
        if (mode == 2 && li == 0) g_shead[n] = 0; // consume chains on layer 2
    }
}

// ---- final layer for sampled rows ONLY (4 samples/wave, same group scheme). ----
__global__ void pull_sampled(const unsigned char* __restrict__ h,
                             const int* __restrict__ users, const int* __restrict__ pos,
                             const int* __restrict__ neg) {
    int gid0 = blockIdx.x * blockDim.x + threadIdx.x;
    int wid  = gid0 >> 6;
    int lane = threadIdx.x & 63;
    int g  = lane >> 4;
    int li = lane & 15;
    int s = wid * 4 + g;
    if (s >= 3 * BATCH) return;
    int which = s >> 12;                         // / BATCH (4096)
    int i     = s & (BATCH - 1);
    const int* idx = (which == 0) ? users : ((which == 1) ? pos : neg);
    int node = idx[i];
    int beg = g_row_ptr[node], end = g_row_ptr[node + 1];
    float dinvN = g_dinv[node];
    float a0 = 0.f, a1 = 0.f, a2 = 0.f, a3 = 0.f;
    for (int k = beg; k < end; k += 4) {
        int k1 = min(k + 1, end - 1);
        int k2 = min(k + 2, end - 1);
        int k3 = min(k + 3, end - 1);
        int s0 = g_csr[k];
        int s1 = g_csr[k1];
        int s2 = g_csr[k2];
        int s3 = g_csr[k3];
        unsigned int d0 = *(const unsigned int*)(h + (size_t)s0 * DIM + li * 4);
        unsigned int d1 = *(const unsigned int*)(h + (size_t)s1 * DIM + li * 4);
        unsigned int d2 = *(const unsigned int*)(h + (size_t)s2 * DIM + li * 4);
        unsigned int d3 = *(const unsigned int*)(h + (size_t)s3 * DIM + li * 4);
        float w1 = (k + 1 < end) ? 1.0f : 0.0f;
        float w2 = (k + 2 < end) ? 1.0f : 0.0f;
        float w3 = (k + 3 < end) ? 1.0f : 0.0f;
        fma4_fp8(d0, 1.0f, a0, a1, a2, a3);
        fma4_fp8(d1, w1, a0, a1, a2, a3);
        fma4_fp8(d2, w2, a0, a1, a2, a3);
        fma4_fp8(d3, w3, a0, a1, a2, a3);
    }
    float gw = dinvN * H_INV_SCALE;
    float* sp = &g_sums[(size_t)s * DIM + li * 4];
    sp[0] += a0 * gw;
    sp[1] += a1 * gw;
    sp[2] += a2 * gw;
    sp[3] += a3 * gw;
}

// ---- per-sample scores + reg; layer-0 (emb) folded in here via u0/p0/n0 ----
__global__ void score_reduce(const float* __restrict__ emb,
                             const int* __restrict__ users, const int* __restrict__ pos,
                             const int* __restrict__ neg) {
    int wid  = (blockIdx.x * blockDim.x + threadIdx.x) >> 6;
    int lane = threadIdx.x & 63;
    if (wid >= BATCH) return;
    float u0 = emb[(size_t)users[wid] * DIM + lane];
    float p0 = emb[(size_t)pos[wid]   * DIM + lane];
    float n0 = emb[(size_t)neg[wid]   * DIM + lane];
    float u = 0.25f * (g_sums[(size_t)wid * DIM + lane] + u0);
    float p = 0.25f * (g_sums[(size_t)(BATCH + wid) * DIM + lane] + p0);
    float n = 0.25f * (g_sums[(size_t)(2 * BATCH + wid) * DIM + lane] + n0);
    float ps = u * p;
    float ns = u * n;
    float rg = u0 * u0 + p0 * p0 + n0 * n0;
    #pragma unroll
    for (int off = 32; off > 0; off >>= 1) {
        ps += __shfl_down(ps, off);
        ns += __shfl_down(ns, off);
        rg += __shfl_down(rg, off);
    }
    if (lane == 0) {
        float x  = ns - ps;
        float sp = fmaxf(x, 0.0f) + log1pf(expf(-fabsf(x)));  // stable softplus
        g_part_sp[wid] = sp;
        g_part_rg[wid] = rg;
    }
}

// ---- single-block final reduction over the 4096 per-wave partials ----
__global__ void final_reduce(float* __restrict__ out) {
    __shared__ float s_sp[256], s_rg[256];
    int t = threadIdx.x;
    float sp = 0.0f, rg = 0.0f;
    for (int i = t; i < BATCH; i += 256) { sp += g_part_sp[i]; rg += g_part_rg[i]; }
    s_sp[t] = sp; s_rg[t] = rg;
    __syncthreads();
    for (int off = 128; off > 0; off >>= 1) {
        if (t < off) { s_sp[t] += s_sp[t + off]; s_rg[t] += s_rg[t + off]; }
        __syncthreads();
    }
    if (t == 0) {
        float loss_emb = s_sp[0] / (float)BATCH;
        float reg      = 0.5f * s_rg[0] / (float)BATCH * REG_WEIGHT;
        out[0] = loss_emb + reg;
        out[1] = loss_emb;
        out[2] = reg;
    }
}

extern "C" void kernel_launch(void* const* d_in, const int* in_sizes, int n_in,
                              void* d_out, int out_size, void* d_ws, size_t ws_size,
                              hipStream_t stream) {
    const float* emb   = (const float*)d_in[0];
    const int*   src   = (const int*)d_in[1];
    const int*   dst   = (const int*)d_in[2];
    const int*   users = (const int*)d_in[3];
    const int*   pos   = (const int*)d_in[4];
    const int*   neg   = (const int*)d_in[5];
    const int E = in_sizes[1];
    float* out = (float*)d_out;

    unsigned char* hf_a;  hipGetSymbolAddress((void**)&hf_a, HIP_SYMBOL(g_hf8));
    unsigned char* hf_b = hf_a + (size_t)N_NODES * DIM;

    const int STAGE_BLOCKS = (E + 1024 * EDGES_PER_THREAD - 1) / (1024 * EDGES_PER_THREAD);
    stage_buckets<<<STAGE_BLOCKS, 1024, 0, stream>>>(src, dst, E, users, pos, neg);
    finalize_place<<<NBUCKET, 512, 0, stream>>>(emb);

    const int NQUAD = (N_NODES + 3) / 4;           // 4 nodes per wave
    const int PULL_BLOCKS = (NQUAD * 64 + 255) / 256;

    // layer 1: full pull + sampled gather (assign) + bcur reset
    pull_layer_fp8<<<PULL_BLOCKS, 256, 0, stream>>>(hf_a, hf_b, 1);

    // layer 2: full pull + sampled gather (accumulate) + chain consume
    pull_layer_fp8<<<PULL_BLOCKS, 256, 0, stream>>>(hf_b, hf_a, 2);

    // layer 3 sampled pull (4 samples/wave)
    const int SAMP_BLOCKS = ((3 * BATCH + 3) / 4 * 64 + 255) / 256;
    pull_sampled<<<SAMP_BLOCKS, 256, 0, stream>>>(hf_a, users, pos, neg);

    score_reduce<<<(BATCH * 64 + 255) / 256, 256, 0, stream>>>(emb, users, pos, neg);
    final_reduce<<<1, 256, 0, stream>>>(out);
}